// Round 11
// baseline (135.329 us; speedup 1.0000x reference)
//
#include <hip/hip_runtime.h>
#include <hip/hip_bf16.h>

#define T_STEPS 24
#define NB      512
#define HID     128
#define INDIM   64
#define BN      16384

typedef __bf16 bf16_t;
typedef __bf16 bf16x8 __attribute__((ext_vector_type(8)));
typedef float  f32x16 __attribute__((ext_vector_type(16)));

__device__ __forceinline__ float rcp_(float x) { return __builtin_amdgcn_rcpf(x); }
__device__ __forceinline__ float sigm_(float x) { return rcp_(1.f + __expf(-x)); }
// tanh(x) = 2*sigm(2x) - 1  (5 inst: mul, exp, add, rcp, fma)
__device__ __forceinline__ float tanh_(float x) { return fmaf(2.f, rcp_(1.f + __expf(-2.f * x)), -1.f); }

#define MF(a, b, c) __builtin_amdgcn_mfma_f32_32x32x16_bf16((a), (b), (c), 0, 0, 0)

// bar1: full drain — x-DMA (vmcnt) complete + LDS visible.
#define BARRIER_FULL() do { \
    asm volatile("s_waitcnt vmcnt(0) lgkmcnt(0)" ::: "memory"); \
    __builtin_amdgcn_s_barrier(); \
    __builtin_amdgcn_sched_barrier(0); \
} while (0)
// bar2: lgkmcnt-only — vmem loads stay in flight.
#define BARRIER_LDS() do { \
    asm volatile("s_waitcnt lgkmcnt(0)" ::: "memory"); \
    __builtin_amdgcn_s_barrier(); \
    __builtin_amdgcn_sched_barrier(0); \
} while (0)

typedef const __attribute__((address_space(1))) unsigned int* gp1_t;
typedef __attribute__((address_space(3))) unsigned int* lp3_t;
#define GLOAD_LDS16(g, l) __builtin_amdgcn_global_load_lds((gp1_t)(g), (lp3_t)(l), 16, 0, 0)

// ---------------------------------------------------------------------------
// Pack kernel (identical since R5, proven). Frag = [64 lanes][8 bf16] = 512 el.
//  Wrz [8ct][16ks]: cols 0..255 = [r|z], K=256 = [emb(128)|h(128)]
//  Win [4ct][8ks]:  i_n rows of Wih (256..383), K=128 (emb)
//  Whn [4ct][8ks]:  h_n rows of Whh (256..383), K=128 (h)
//  WmP [4ct][4ks]:  W_mlp, K=64 (x)
//  bc  [512] f32:   [0..255]=bih+bhh (rz), [256..383]=bih_n, [384..511]=bhh_n
// ---------------------------------------------------------------------------
__global__ void pack_kernel(const float* __restrict__ Wm,
                            const float* __restrict__ Wih, const float* __restrict__ Whh,
                            const float* __restrict__ bih, const float* __restrict__ bhh,
                            bf16_t* __restrict__ Wrz, bf16_t* __restrict__ Win,
                            bf16_t* __restrict__ Whn, bf16_t* __restrict__ WmP,
                            float* __restrict__ bc)
{
    int tid = blockIdx.x * 256 + threadIdx.x;
    if (tid < 65536) {                         // Wrz
        int e = tid & 7, l = (tid >> 3) & 63, ks = (tid >> 9) & 15, ct = tid >> 13;
        int col = ct * 32 + (l & 31);
        int k   = ks * 16 + ((l >> 5) << 3) + e;
        float v = (k < 128) ? Wih[col * HID + k] : Whh[col * HID + (k - 128)];
        Wrz[tid] = (bf16_t)v;
    } else if (tid < 81920) {                  // Win
        int u = tid - 65536;
        int e = u & 7, l = (u >> 3) & 63, ks = (u >> 9) & 7, ct = u >> 12;
        int col = ct * 32 + (l & 31);
        int k   = ks * 16 + ((l >> 5) << 3) + e;
        Win[u] = (bf16_t)Wih[(256 + col) * HID + k];
    } else if (tid < 98304) {                  // Whn
        int u = tid - 81920;
        int e = u & 7, l = (u >> 3) & 63, ks = (u >> 9) & 7, ct = u >> 12;
        int col = ct * 32 + (l & 31);
        int k   = ks * 16 + ((l >> 5) << 3) + e;
        Whn[u] = (bf16_t)Whh[(256 + col) * HID + k];
    } else if (tid < 106496) {                 // WmP
        int u = tid - 98304;
        int e = u & 7, l = (u >> 3) & 63, ks = (u >> 9) & 3, ct = u >> 11;
        int col = ct * 32 + (l & 31);
        int k   = ks * 16 + ((l >> 5) << 3) + e;
        WmP[u] = (bf16_t)Wm[col * INDIM + k];
    } else if (tid < 107008) {                 // bc
        int j = tid - 106496;
        float v;
        if (j < 256)      v = bih[j] + bhh[j];
        else if (j < 384) v = bih[j];
        else              v = bhh[j - 128];
        bc[j] = v;
    }
}

// ---------------------------------------------------------------------------
// Persistent GRU: 256 blocks x 512 threads (8 waves, 2/SIMD), 64 rows/block.
// R11 = R10 with phase B split: the h-half of the gate GEMM (needs only hsC,
// ready at bar1) runs BEFORE phase A -> its 24 MFMAs + 16 Wrz-h L2 loads
// overlap phase A's xs/LDS latency; the e-half runs after bar2. The Wrz
// stream is split into two latency-covered halves. Same math (commutative
// accumulation), same LDS/swizzles.
// ---------------------------------------------------------------------------
__global__ __launch_bounds__(512)
__attribute__((amdgpu_waves_per_eu(2, 2)))
void gru_all(
    const float*  __restrict__ x, float* __restrict__ out,
    const bf16_t* __restrict__ Wrz, const bf16_t* __restrict__ Win,
    const bf16_t* __restrict__ Whn, const bf16_t* __restrict__ WmP,
    const float*  __restrict__ bc,  const float* __restrict__ bm)
{
    __shared__ __align__(16) char WinS[32768];
    __shared__ __align__(16) char WhnS[32768];
    __shared__ __align__(16) char WmPS[16384];
    __shared__ __align__(16) char es  [16384];
    __shared__ __align__(16) char hs0 [16384], hs1[16384];
    __shared__ __align__(16) char xs  [16384];   // 64 x 64 fp32, swizzled

    const int tid = threadIdx.x;          // 0..511
    const int l   = tid & 63;
    const int w   = tid >> 6;             // 0..7
    const int rt  = w >> 2;               // rowtile 0/1
    const int ct  = w & 3;                // gate coltile
    const int r0  = blockIdx.x * 64;
    const int b   = r0 >> 9;
    const int n0  = r0 & (NB - 1);

    const int lane31 = l & 31;
    const int hi     = l >> 5;
    const int rA     = rt * 32 + lane31;
    const int sw0    = (lane31 & 15) << 4;
    const int jh     = ct * 32 + lane31;

    // ---- x-DMA per-lane source offsets (bytes) + wave-uniform LDS dests
    const int rowD0 = w * 8 + (l >> 4);          // instruction 0 row
    const int rowD1 = rowD0 + 4;                 // instruction 1 row
    const int oD0   = rowD0 * 256 + ((((l & 15) ^ (rowD0 & 15))) << 4);
    const int oD1   = rowD1 * 256 + ((((l & 15) ^ (rowD1 & 15))) << 4);
    const char* xb0 = (const char*)(x + ((size_t)b * T_STEPS * NB + n0) * INDIM);
    char* ldst = xs + w * 2048;

    // ---- stage x(0) DMA first (longest latency)
    GLOAD_LDS16(xb0 + oD0, ldst);
    GLOAD_LDS16(xb0 + oD1, ldst + 1024);

    // ---- stage step-invariant weight caches; zero hs0 (h(0)=0)
    {
        const uint4* s; uint4* d;
        s = (const uint4*)Win; d = (uint4*)WinS;
        for (int i = tid; i < 2048; i += 512) d[i] = s[i];
        s = (const uint4*)Whn; d = (uint4*)WhnS;
        for (int i = tid; i < 2048; i += 512) d[i] = s[i];
        s = (const uint4*)WmP; d = (uint4*)WmPS;
        for (int i = tid; i < 1024; i += 512) d[i] = s[i];
        uint4 z4 = make_uint4(0, 0, 0, 0);
        for (int i = tid; i < 1024; i += 512) ((uint4*)hs0)[i] = z4;
    }

    const float bRr = bc[jh], bRz = bc[128 + jh];
    const float bIN = bc[256 + jh], bHN = bc[384 + jh];
    const float bmv = bm[jh];

    const bf16_t* wrR = Wrz + (ct * 16) * 512 + l * 8;       // r coltile base
    const bf16_t* wrZ = Wrz + ((ct + 4) * 16) * 512 + l * 8; // z coltile base
    #define LDG(p) (*(const bf16x8*)(p))

    f32x16 h = {};

    #pragma unroll 1
    for (int t = 0; t < T_STEPS; ++t) {
        const char* hsC = (t & 1) ? hs1 : hs0;
        char*       hsN = (t & 1) ? hs0 : hs1;
        BARRIER_FULL();                   // x(t) DMA complete; hs(t) visible

        // ---- gate accumulators (biases folded into C-init)
        f32x16 ar, az, ai, ah;
        #pragma unroll
        for (int q = 0; q < 16; ++q) { ar[q] = bRr; az[q] = bRz; ai[q] = bIN; ah[q] = bHN; }

        // ---- phase B-h: h-half of gate GEMM (only needs hsC, ready now).
        // Its 24 MFMAs + 16 Wrz-h L2 loads overlap phase A's LDS latency.
        #pragma unroll 2
        for (int kk = 0; kk < 8; ++kk) {
            int off = ((kk * 2 + hi) * 16) ^ sw0;
            bf16x8 aH  = *(const bf16x8*)(hsC + rA * 256 + off);
            bf16x8 bRh = LDG(wrR + (8 + kk) * 512);
            bf16x8 bZh = LDG(wrZ + (8 + kk) * 512);
            bf16x8 bN  = *(const bf16x8*)(WhnS + (ct * 8 + kk) * 1024 + l * 16);
            ar = MF(aH, bRh, ar);
            az = MF(aH, bZh, az);
            ah = MF(aH, bN,  ah);
        }

        // ---- phase A: emb tile = relu(x @ Wm^T + bm); x from swizzled LDS
        f32x16 accA;
        #pragma unroll
        for (int q = 0; q < 16; ++q) accA[q] = bmv;
        const int sAr = rA * 256;
        #define PHA(ks) { \
            int g0 = ((ks) * 4 + hi * 2) * 16; \
            float4 fa = *(const float4*)(xs + sAr + (g0 ^ sw0)); \
            float4 fb = *(const float4*)(xs + sAr + ((g0 + 16) ^ sw0)); \
            union { bf16_t h8[8]; bf16x8 v; } pa; \
            pa.h8[0] = (bf16_t)fa.x; pa.h8[1] = (bf16_t)fa.y; \
            pa.h8[2] = (bf16_t)fa.z; pa.h8[3] = (bf16_t)fa.w; \
            pa.h8[4] = (bf16_t)fb.x; pa.h8[5] = (bf16_t)fb.y; \
            pa.h8[6] = (bf16_t)fb.z; pa.h8[7] = (bf16_t)fb.w; \
            bf16x8 bfr = *(const bf16x8*)(WmPS + (ct * 4 + (ks)) * 1024 + l * 16); \
            accA = MF(pa.v, bfr, accA); }
        PHA(0) PHA(1) PHA(2) PHA(3)
        #undef PHA
        #pragma unroll
        for (int q = 0; q < 16; ++q) {
            int rl  = (q & 3) + ((q >> 2) << 3) + (hi << 2);
            int row = rt * 32 + rl;
            *(bf16_t*)(es + row * 256 + ((jh * 2) ^ ((rl & 15) << 4))) =
                (bf16_t)fmaxf(accA[q], 0.f);
        }

        BARRIER_LDS();                    // es ready; all xs reads drained

        // ---- issue x(t+1) DMA (overwrites xs; safe after bar2)
        if (t + 1 < T_STEPS) {
            const char* xbn = xb0 + (size_t)(t + 1) * NB * INDIM * 4;
            GLOAD_LDS16(xbn + oD0, ldst);
            GLOAD_LDS16(xbn + oD1, ldst + 1024);
        }

        // ---- phase B-e: emb-half of gate GEMM
        #pragma unroll 2
        for (int kk = 0; kk < 8; ++kk) {
            int off = ((kk * 2 + hi) * 16) ^ sw0;
            bf16x8 aE  = *(const bf16x8*)(es + rA * 256 + off);
            bf16x8 bRe = LDG(wrR + kk * 512);
            bf16x8 bZe = LDG(wrZ + kk * 512);
            bf16x8 bI  = *(const bf16x8*)(WinS + (ct * 8 + kk) * 1024 + l * 16);
            ar = MF(aE, bRe, ar);
            az = MF(aE, bZe, az);
            ai = MF(aE, bI,  ai);
        }

        // ---- phase C: lane-local gates (rcp-based) + h update -> hsN (bf16)
        #pragma unroll
        for (int q = 0; q < 16; ++q) {
            int rl  = (q & 3) + ((q >> 2) << 3) + (hi << 2);
            int row = rt * 32 + rl;
            float r  = sigm_(ar[q]);
            float z  = sigm_(az[q]);
            float n  = tanh_(ai[q] + r * ah[q]);
            float hv = n + z * (h[q] - n);
            h[q] = hv;
            *(bf16_t*)(hsN + row * 256 + ((jh * 2) ^ ((rl & 15) << 4))) = (bf16_t)hv;
        }
    }

    // ---- final store (fp32) straight from registers
    #pragma unroll
    for (int q = 0; q < 16; ++q) {
        int rl = (q & 3) + ((q >> 2) << 3) + (hi << 2);
        out[(size_t)(r0 + rt * 32 + rl) * HID + jh] = h[q];
    }
    #undef LDG
}

// ---------------------------------------------------------------------------
extern "C" void kernel_launch(void* const* d_in, const int* in_sizes, int n_in,
                              void* d_out, int out_size, void* d_ws, size_t ws_size,
                              hipStream_t stream)
{
    const float* x   = (const float*)d_in[0];
    const float* Wm  = (const float*)d_in[1];
    const float* bm  = (const float*)d_in[2];
    const float* Wih = (const float*)d_in[3];
    const float* Whh = (const float*)d_in[4];
    const float* bih = (const float*)d_in[5];
    const float* bhh = (const float*)d_in[6];

    char* ws = (char*)d_ws;
    bf16_t* Wrz = (bf16_t*)(ws);                 // 131072 B
    bf16_t* Win = (bf16_t*)(ws + 131072);        //  32768 B
    bf16_t* Whn = (bf16_t*)(ws + 163840);        //  32768 B
    bf16_t* WmP = (bf16_t*)(ws + 196608);        //  16384 B
    float*  bcp = (float*) (ws + 212992);        //   2048 B

    pack_kernel<<<418, 256, 0, stream>>>(Wm, Wih, Whh, bih, bhh, Wrz, Win, Whn, WmP, bcp);
    gru_all<<<256, 512, 0, stream>>>(x, (float*)d_out, Wrz, Win, Whn, WmP, bcp, bm);
}

// Round 12
// 123.470 us; speedup vs baseline: 1.0960x; 1.0960x over previous
//
#include <hip/hip_runtime.h>
#include <hip/hip_bf16.h>

#define T_STEPS 24
#define NB      512
#define HID     128
#define INDIM   64
#define BN      16384

typedef __bf16 bf16_t;
typedef __bf16 bf16x8 __attribute__((ext_vector_type(8)));
typedef float  f32x16 __attribute__((ext_vector_type(16)));

__device__ __forceinline__ float rcp_(float x) { return __builtin_amdgcn_rcpf(x); }
__device__ __forceinline__ float sigm_(float x) { return rcp_(1.f + __expf(-x)); }
__device__ __forceinline__ float tanh_(float x) { return fmaf(2.f, rcp_(1.f + __expf(-2.f * x)), -1.f); }

#define MF(a, b, c) __builtin_amdgcn_mfma_f32_32x32x16_bf16((a), (b), (c), 0, 0, 0)

// lgkmcnt-only barrier: LDS writes visible, vmem loads stay in flight.
#define BARRIER_LDS() do { \
    asm volatile("s_waitcnt lgkmcnt(0)" ::: "memory"); \
    __builtin_amdgcn_s_barrier(); \
    __builtin_amdgcn_sched_barrier(0); \
} while (0)

// ---------------------------------------------------------------------------
// Pack kernel (identical since R5, proven). Frag = [64 lanes][8 bf16] = 512 el.
//  Wrz [8ct][16ks]: cols 0..255 = [r|z], K=256 = [emb(128)|h(128)]
//  Win [4ct][8ks]:  i_n rows of Wih (256..383), K=128 (emb)
//  Whn [4ct][8ks]:  h_n rows of Whh (256..383), K=128 (h)
//  WmP [4ct][4ks]:  W_mlp, K=64 (x)
//  bc  [512] f32:   [0..255]=bih+bhh (rz), [256..383]=bih_n, [384..511]=bhh_n
// ---------------------------------------------------------------------------
__global__ void pack_kernel(const float* __restrict__ Wm,
                            const float* __restrict__ Wih, const float* __restrict__ Whh,
                            const float* __restrict__ bih, const float* __restrict__ bhh,
                            bf16_t* __restrict__ Wrz, bf16_t* __restrict__ Win,
                            bf16_t* __restrict__ Whn, bf16_t* __restrict__ WmP,
                            float* __restrict__ bc)
{
    int tid = blockIdx.x * 256 + threadIdx.x;
    if (tid < 65536) {                         // Wrz
        int e = tid & 7, l = (tid >> 3) & 63, ks = (tid >> 9) & 15, ct = tid >> 13;
        int col = ct * 32 + (l & 31);
        int k   = ks * 16 + ((l >> 5) << 3) + e;
        float v = (k < 128) ? Wih[col * HID + k] : Whh[col * HID + (k - 128)];
        Wrz[tid] = (bf16_t)v;
    } else if (tid < 81920) {                  // Win
        int u = tid - 65536;
        int e = u & 7, l = (u >> 3) & 63, ks = (u >> 9) & 7, ct = u >> 12;
        int col = ct * 32 + (l & 31);
        int k   = ks * 16 + ((l >> 5) << 3) + e;
        Win[u] = (bf16_t)Wih[(256 + col) * HID + k];
    } else if (tid < 98304) {                  // Whn
        int u = tid - 81920;
        int e = u & 7, l = (u >> 3) & 63, ks = (u >> 9) & 7, ct = u >> 12;
        int col = ct * 32 + (l & 31);
        int k   = ks * 16 + ((l >> 5) << 3) + e;
        Whn[u] = (bf16_t)Whh[(256 + col) * HID + k];
    } else if (tid < 106496) {                 // WmP
        int u = tid - 98304;
        int e = u & 7, l = (u >> 3) & 63, ks = (u >> 9) & 3, ct = u >> 11;
        int col = ct * 32 + (l & 31);
        int k   = ks * 16 + ((l >> 5) << 3) + e;
        WmP[u] = (bf16_t)Wm[col * INDIM + k];
    } else if (tid < 107008) {                 // bc
        int j = tid - 106496;
        float v;
        if (j < 256)      v = bih[j] + bhh[j];
        else if (j < 384) v = bih[j];
        else              v = bhh[j - 128];
        bc[j] = v;
    }
}

// ---------------------------------------------------------------------------
// R12: cross-step pipelined persistent GRU. 256 blocks x 512 thr (8 waves).
// Per step, ONE lgkm barrier:
//   bar -> B(t){es[t&1],hs[t&1]} -> issue x(t+2) -> A(t+1)->es[~] -> C(t)->hs[~]
//       -> cvt+write x(t+2)->xs[t&1]
// es/hs/xs double-buffered; xs is bf16 (staged via regs, T14 split);
// WmP lives in 4 persistent reg frags. LDS = 144 KiB.
// ---------------------------------------------------------------------------
__global__ __launch_bounds__(512)
__attribute__((amdgpu_waves_per_eu(2, 2)))
void gru_all(
    const float*  __restrict__ x, float* __restrict__ out,
    const bf16_t* __restrict__ Wrz, const bf16_t* __restrict__ Win,
    const bf16_t* __restrict__ Whn, const bf16_t* __restrict__ WmP,
    const float*  __restrict__ bc,  const float* __restrict__ bm)
{
    __shared__ __align__(16) char WinS[32768];
    __shared__ __align__(16) char WhnS[32768];
    __shared__ __align__(16) char es0[16384], es1[16384];
    __shared__ __align__(16) char hs0[16384], hs1[16384];
    __shared__ __align__(16) char xs0[8192],  xs1[8192];   // 64 rows x 128B bf16

    const int tid = threadIdx.x;          // 0..511
    const int l   = tid & 63;
    const int w   = tid >> 6;             // 0..7
    const int rt  = w >> 2;               // rowtile 0/1
    const int ct  = w & 3;                // gate coltile
    const int r0  = blockIdx.x * 64;
    const int b   = r0 >> 9;
    const int n0  = r0 & (NB - 1);

    const int lane31 = l & 31;
    const int hi     = l >> 5;
    const int rA     = rt * 32 + lane31;
    const int sw0    = (lane31 & 15) << 4;
    const int jh     = ct * 32 + lane31;

    // ---- x staging geometry: thread covers row xrow, 16B slot xslot of xs
    const int xrow  = w * 8 + (l >> 3);          // 0..63
    const int xslot = l & 7;                     // 0..7
    const int xsWr  = xrow * 128 + (((xslot ^ (xrow & 7))) << 4);
    const char* xb0 = (const char*)(x + ((size_t)b * T_STEPS * NB + n0) * INDIM);
    const int  xgOff = xrow * 256 + xslot * 32;  // bytes within one t-slab
    const size_t xstep = (size_t)NB * INDIM * 4; // 128 KiB per t

    // ---- stage step-invariant weights; zero hs0
    {
        const uint4* s; uint4* d;
        s = (const uint4*)Win; d = (uint4*)WinS;
        for (int i = tid; i < 2048; i += 512) d[i] = s[i];
        s = (const uint4*)Whn; d = (uint4*)WhnS;
        for (int i = tid; i < 2048; i += 512) d[i] = s[i];
        uint4 z4 = make_uint4(0, 0, 0, 0);
        for (int i = tid; i < 1024; i += 512) ((uint4*)hs0)[i] = z4;
    }
    // WmP: 4 persistent register fragments (ct-specific)
    bf16x8 wmp0 = *(const bf16x8*)(WmP + (ct * 4 + 0) * 512 + l * 8);
    bf16x8 wmp1 = *(const bf16x8*)(WmP + (ct * 4 + 1) * 512 + l * 8);
    bf16x8 wmp2 = *(const bf16x8*)(WmP + (ct * 4 + 2) * 512 + l * 8);
    bf16x8 wmp3 = *(const bf16x8*)(WmP + (ct * 4 + 3) * 512 + l * 8);

    const float bRr = bc[jh], bRz = bc[128 + jh];
    const float bIN = bc[256 + jh], bHN = bc[384 + jh];
    const float bmv = bm[jh];

    const bf16_t* wrR = Wrz + (ct * 16) * 512 + l * 8;       // r coltile base
    const bf16_t* wrZ = Wrz + ((ct + 4) * 16) * 512 + l * 8; // z coltile base
    #define LDG(p) (*(const bf16x8*)(p))

    // x stage helpers
    #define XLOAD(T_, A_, B_) { \
        const char* xp = xb0 + (size_t)(T_) * xstep + xgOff; \
        A_ = *(const float4*)(xp); B_ = *(const float4*)(xp + 16); }
    #define XWRITE(DST, A_, B_) { \
        union { bf16_t h8[8]; uint4 u; } pk; \
        pk.h8[0] = (bf16_t)(A_).x; pk.h8[1] = (bf16_t)(A_).y; \
        pk.h8[2] = (bf16_t)(A_).z; pk.h8[3] = (bf16_t)(A_).w; \
        pk.h8[4] = (bf16_t)(B_).x; pk.h8[5] = (bf16_t)(B_).y; \
        pk.h8[6] = (bf16_t)(B_).z; pk.h8[7] = (bf16_t)(B_).w; \
        *(uint4*)((DST) + xsWr) = pk.u; }

    // phase A: emb tile from xs (bf16) -> es  (wmp regs, bias folded)
    #define PHASE_A(XSRC, EDST) { \
        f32x16 accA; \
        _Pragma("unroll") for (int q = 0; q < 16; ++q) accA[q] = bmv; \
        { bf16x8 a0 = *(const bf16x8*)((XSRC) + rA * 128 + ((((0*2+hi) ^ (rA & 7))) << 4)); \
          accA = MF(a0, wmp0, accA); \
          bf16x8 a1 = *(const bf16x8*)((XSRC) + rA * 128 + ((((1*2+hi) ^ (rA & 7))) << 4)); \
          accA = MF(a1, wmp1, accA); \
          bf16x8 a2 = *(const bf16x8*)((XSRC) + rA * 128 + ((((2*2+hi) ^ (rA & 7))) << 4)); \
          accA = MF(a2, wmp2, accA); \
          bf16x8 a3 = *(const bf16x8*)((XSRC) + rA * 128 + ((((3*2+hi) ^ (rA & 7))) << 4)); \
          accA = MF(a3, wmp3, accA); } \
        _Pragma("unroll") for (int q = 0; q < 16; ++q) { \
            int rl  = (q & 3) + ((q >> 2) << 3) + (hi << 2); \
            int row = rt * 32 + rl; \
            *(bf16_t*)((EDST) + row * 256 + ((jh * 2) ^ ((rl & 15) << 4))) = \
                (bf16_t)fmaxf(accA[q], 0.f); } }

    f32x16 h = {};

    // ---- prologue: x(0) -> xs0; A(0) -> es0; x(1) -> xs1
    {
        float4 pa, pb;
        XLOAD(0, pa, pb);
        XWRITE(xs0, pa, pb);
        float4 pc, pd;
        XLOAD(1, pc, pd);
        BARRIER_LDS();                    // xs0 / hs0 / Win / Whn visible
        PHASE_A(xs0, es0);
        XWRITE(xs1, pc, pd);
    }

    #pragma unroll 1
    for (int t = 0; t < T_STEPS; ++t) {
        const char* esC = (t & 1) ? es1 : es0;
        char*       esN = (t & 1) ? es0 : es1;
        const char* hsC = (t & 1) ? hs1 : hs0;
        char*       hsN = (t & 1) ? hs0 : hs1;
        char*       xsW = (t & 1) ? xs1 : xs0;   // dest for x(t+2)
        const char* xsA = (t & 1) ? xs0 : xs1;   // src for A(t+1)

        BARRIER_LDS();   // es[t&1] (A of t-1), hs[t&1] (C of t-1), xs writes visible

        // ---- B(t): full gate GEMM; all operands ready at barrier exit
        f32x16 ar, az, ai, ah;
        #pragma unroll
        for (int q = 0; q < 16; ++q) { ar[q] = bRr; az[q] = bRz; ai[q] = bIN; ah[q] = bHN; }
        #pragma unroll 2
        for (int kk = 0; kk < 8; ++kk) {
            int off = ((kk * 2 + hi) * 16) ^ sw0;
            bf16x8 aE  = *(const bf16x8*)(esC + rA * 256 + off);
            bf16x8 aH  = *(const bf16x8*)(hsC + rA * 256 + off);
            bf16x8 bRe = LDG(wrR + kk * 512);
            bf16x8 bRh = LDG(wrR + (8 + kk) * 512);
            bf16x8 bZe = LDG(wrZ + kk * 512);
            bf16x8 bZh = LDG(wrZ + (8 + kk) * 512);
            bf16x8 bI  = *(const bf16x8*)(WinS + (ct * 8 + kk) * 1024 + l * 16);
            bf16x8 bN  = *(const bf16x8*)(WhnS + (ct * 8 + kk) * 1024 + l * 16);
            ar = MF(aE, bRe, ar); ar = MF(aH, bRh, ar);
            az = MF(aE, bZe, az); az = MF(aH, bZh, az);
            ai = MF(aE, bI,  ai); ah = MF(aH, bN,  ah);
        }

        // ---- issue x(t+2) loads (land under A/C)
        float4 pxA, pxB;
        const bool havex = (t + 2 < T_STEPS);
        if (havex) XLOAD(t + 2, pxA, pxB);

        // ---- A(t+1): emb for next step (independent of B/C results)
        if (t + 1 < T_STEPS) PHASE_A(xsA, esN);

        // ---- C(t): lane-local gates + h update -> hsN (bf16)
        #pragma unroll
        for (int q = 0; q < 16; ++q) {
            int rl  = (q & 3) + ((q >> 2) << 3) + (hi << 2);
            int row = rt * 32 + rl;
            float r  = sigm_(ar[q]);
            float z  = sigm_(az[q]);
            float n  = tanh_(ai[q] + r * ah[q]);
            float hv = n + z * (h[q] - n);
            h[q] = hv;
            *(bf16_t*)(hsN + row * 256 + ((jh * 2) ^ ((rl & 15) << 4))) = (bf16_t)hv;
        }

        // ---- write x(t+2) into xs[t&1] (read by A(t+2) after next barrier)
        if (havex) XWRITE(xsW, pxA, pxB);
    }

    // ---- final store (fp32) straight from registers
    #pragma unroll
    for (int q = 0; q < 16; ++q) {
        int rl = (q & 3) + ((q >> 2) << 3) + (hi << 2);
        out[(size_t)(r0 + rt * 32 + rl) * HID + jh] = h[q];
    }
    #undef LDG
    #undef XLOAD
    #undef XWRITE
    #undef PHASE_A
}

// ---------------------------------------------------------------------------
extern "C" void kernel_launch(void* const* d_in, const int* in_sizes, int n_in,
                              void* d_out, int out_size, void* d_ws, size_t ws_size,
                              hipStream_t stream)
{
    const float* x   = (const float*)d_in[0];
    const float* Wm  = (const float*)d_in[1];
    const float* bm  = (const float*)d_in[2];
    const float* Wih = (const float*)d_in[3];
    const float* Whh = (const float*)d_in[4];
    const float* bih = (const float*)d_in[5];
    const float* bhh = (const float*)d_in[6];

    char* ws = (char*)d_ws;
    bf16_t* Wrz = (bf16_t*)(ws);                 // 131072 B
    bf16_t* Win = (bf16_t*)(ws + 131072);        //  32768 B
    bf16_t* Whn = (bf16_t*)(ws + 163840);        //  32768 B
    bf16_t* WmP = (bf16_t*)(ws + 196608);        //  16384 B
    float*  bcp = (float*) (ws + 212992);        //   2048 B

    pack_kernel<<<418, 256, 0, stream>>>(Wm, Wih, Whh, bih, bhh, Wrz, Win, Whn, WmP, bcp);
    gru_all<<<256, 512, 0, stream>>>(x, (float*)d_out, Wrz, Win, Whn, WmP, bcp, bm);
}